// Round 15
// baseline (161.295 us; speedup 1.0000x reference)
//
#include <hip/hip_runtime.h>
#include <stdint.h>

#define DM 1024
#define HEADS 16
#define DH 64
#define BQ 4
#define TT 2048
#define MTOT (BQ*TT)  // 8192
#define NQT (TT/64)   // 32 q-tiles per (b,h)

typedef __attribute__((ext_vector_type(8))) __bf16 bf16x8;
typedef __attribute__((ext_vector_type(4))) float f32x4;
typedef __attribute__((ext_vector_type(4))) uint32_t u32x4;
typedef unsigned short u16;
typedef __attribute__((ext_vector_type(8))) unsigned short u16x8;

__device__ __forceinline__ u16 f2b(float f) {
  uint32_t u = __builtin_bit_cast(uint32_t, f);
  u = (u + 0x7fffu + ((u >> 16) & 1u)) >> 16;
  return (u16)u;
}

__device__ __forceinline__ uint32_t cvtpk(float lo, float hi) {
  uint32_t r;
  asm("v_cvt_pk_bf16_f32 %0, %1, %2" : "=v"(r) : "v"(lo), "v"(hi));
  return r;
}

__device__ __forceinline__ void gload_lds16(const u16* g, u16* l) {
  __builtin_amdgcn_global_load_lds(
      (const __attribute__((address_space(1))) void*)g,
      (__attribute__((address_space(3))) void*)l, 16, 0, 0);
}

// ---------------- fused cast: x, Wq|Wk|Wv (contiguous), Wo -> bf16 ----------------
#define NX (MTOT * DM / 4)   // float4s in x
#define NW (DM * DM / 4)     // float4s per weight matrix
__global__ __launch_bounds__(256) void cast_all(const float* __restrict__ x,
                                                const float* __restrict__ Wq,
                                                const float* __restrict__ Wk,
                                                const float* __restrict__ Wv,
                                                const float* __restrict__ Wo,
                                                u16* __restrict__ xb,
                                                u16* __restrict__ wqkvb,
                                                u16* __restrict__ wob) {
  int i = blockIdx.x * 256 + threadIdx.x;
  const float* src; u16* dst;
  if (i < NX)               { src = x;  dst = xb; }
  else if (i < NX + NW)     { src = Wq; dst = wqkvb;          i -= NX; }
  else if (i < NX + 2 * NW) { src = Wk; dst = wqkvb + 4 * NW; i -= NX + NW; }
  else if (i < NX + 3 * NW) { src = Wv; dst = wqkvb + 8 * NW; i -= NX + 2 * NW; }
  else                      { src = Wo; dst = wob;            i -= NX + 3 * NW; }
  float4 v = ((const float4*)src)[i];
  ushort4 o;
  o.x = f2b(v.x); o.y = f2b(v.y); o.z = f2b(v.z); o.w = f2b(v.w);
  ((ushort4*)dst)[i] = o;
}

// ---------------- fused QKV GEMM on the out8 template (unchanged, round 14) ---
#define SLOT_QA (256 * 32)
#define SLOT_QB (128 * 32)
#define SLOT_QE (SLOT_QA + SLOT_QB)  // 12288 elems (24KB)

__global__ __launch_bounds__(512, 2) void gemm_qkv8(const u16* __restrict__ A,
                                                    const u16* __restrict__ W,
                                                    const float* __restrict__ bq,
                                                    const float* __restrict__ bk,
                                                    const float* __restrict__ bv,
                                                    u16* __restrict__ Qo,
                                                    u16* __restrict__ Ko,
                                                    u16* __restrict__ Vto,
                                                    float qs) {
  __shared__ u16 lds[4 * SLOT_QE];  // 96 KB
  const int tid = threadIdx.x, lane = tid & 63, wave = tid >> 6;
  const int fr = lane & 15, g = lane >> 4;
  const int wm = wave >> 1, wn = wave & 1;

  // XCD swizzle: 768 = 8 * 96
  int bid = blockIdx.x;
  bid = (bid & 7) * 96 + (bid >> 3);
  const int by = bid / 24, bx = bid % 24;       // by: m-tile(32), bx: n-tile(24)
  const int m0 = by * 256, n0 = bx * 128;

  const int srow = tid >> 2;                    // 0..127
  const int schunk = (tid & 3) ^ ((tid >> 3) & 3);
  const u16* gA0 = A + (size_t)(m0 + srow) * DM + schunk * 8;
  const u16* gA1 = gA0 + (size_t)128 * DM;
  const u16* gB0 = W + (size_t)(n0 + srow) * DM + schunk * 8;
  const int dA0 = wave * 512;
  const int dA1 = 4096 + wave * 512;
  const int dB0 = SLOT_QA + wave * 512;

#define STAGEQ(slot, kt) {                                   \
    u16* ls = &lds[(slot) * SLOT_QE];                        \
    const int ke = (kt) * 32;                                \
    gload_lds16(gA0 + ke, ls + dA0);                         \
    gload_lds16(gA1 + ke, ls + dA1);                         \
    gload_lds16(gB0 + ke, ls + dB0); }

  const int rchunk = (g ^ ((fr >> 1) & 3)) * 8;
  const int offA = (wm * 64 + fr) * 32 + rchunk;
  const int offB = SLOT_QA + (wn * 64 + fr) * 32 + rchunk;

  f32x4 acc[4][4];
#pragma unroll
  for (int mi = 0; mi < 4; ++mi)
#pragma unroll
    for (int ni = 0; ni < 4; ++ni) acc[mi][ni] = (f32x4){0.f, 0.f, 0.f, 0.f};

  bf16x8 afA[4], bfA[4], afB[4], bfB[4];

#define READQ(AFv, BFv, kt) {                                \
    const u16* sl = &lds[((kt) & 3) * SLOT_QE];              \
    _Pragma("unroll")                                        \
    for (int mi = 0; mi < 4; ++mi)                           \
      AFv[mi] = *(const bf16x8*)&sl[offA + mi * 512];        \
    _Pragma("unroll")                                        \
    for (int ni = 0; ni < 4; ++ni)                           \
      BFv[ni] = *(const bf16x8*)&sl[offB + ni * 512]; }

#define MFMAQ(AFv, BFv) {                                    \
    __builtin_amdgcn_s_setprio(1);                           \
    _Pragma("unroll")                                        \
    for (int mi = 0; mi < 4; ++mi)                           \
      _Pragma("unroll")                                      \
      for (int ni = 0; ni < 4; ++ni)                         \
        acc[mi][ni] = __builtin_amdgcn_mfma_f32_16x16x32_bf16(AFv[mi], BFv[ni], acc[mi][ni], 0, 0, 0); \
    __builtin_amdgcn_s_setprio(0); }

#define QW3 asm volatile("s_waitcnt vmcnt(3)" ::: "memory"); \
            asm volatile("s_barrier" ::: "memory");
#define QW0 asm volatile("s_waitcnt vmcnt(0)" ::: "memory"); \
            asm volatile("s_barrier" ::: "memory");

  STAGEQ(0, 0)
  STAGEQ(1, 1)
  STAGEQ(2, 2)
  asm volatile("s_waitcnt vmcnt(6)" ::: "memory");
  asm volatile("s_barrier" ::: "memory");
  READQ(afA, bfA, 0)

  for (int kt = 0; kt < 28; kt += 2) {
    QW3
    READQ(afB, bfB, kt + 1)
    MFMAQ(afA, bfA)
    STAGEQ((kt + 3) & 3, kt + 3)
    QW3
    READQ(afA, bfA, kt + 2)
    MFMAQ(afB, bfB)
    STAGEQ((kt + 4) & 3, kt + 4)
  }
  QW3
  READQ(afB, bfB, 29)
  MFMAQ(afA, bfA)          // kt=28
  STAGEQ(3, 31)
  QW3
  READQ(afA, bfA, 30)
  MFMAQ(afB, bfB)          // kt=29
  QW0
  READQ(afB, bfB, 31)
  MFMAQ(afA, bfA)          // kt=30
  MFMAQ(afB, bfB)          // kt=31

  const int g4 = g * 4;
  const int seg = n0 >> 10;
  const int nbase = (n0 & 1023) + wn * 64 + fr;
  if (seg == 0) {
#pragma unroll
    for (int ni = 0; ni < 4; ++ni) {
      const int cgl = nbase + ni * 16;
      const float bb = bq[cgl];
      const int hh = cgl >> 6, d = cgl & 63;
#pragma unroll
      for (int mi = 0; mi < 4; ++mi) {
        const int m = m0 + wm * 64 + mi * 16 + g4;
        const int bi = m >> 11, t = m & 2047;
        u16* dst = &Qo[(((size_t)bi * HEADS + hh) * TT + t) * DH + d];
#pragma unroll
        for (int j = 0; j < 4; ++j)
          dst[(size_t)j * DH] = f2b((acc[mi][ni][j] + bb) * qs);
      }
    }
  } else if (seg == 1) {
#pragma unroll
    for (int ni = 0; ni < 4; ++ni) {
      const int cgl = nbase + ni * 16;
      const float bb = bk[cgl];
      const int hh = cgl >> 6, d = cgl & 63;
#pragma unroll
      for (int mi = 0; mi < 4; ++mi) {
        const int m = m0 + wm * 64 + mi * 16 + g4;
        const int bi = m >> 11, t = m & 2047;
        u16* dst = &Ko[(((size_t)bi * HEADS + hh) * TT + t) * DH + d];
#pragma unroll
        for (int j = 0; j < 4; ++j)
          dst[(size_t)j * DH] = f2b(acc[mi][ni][j] + bb);
      }
    }
  } else {
#pragma unroll
    for (int ni = 0; ni < 4; ++ni) {
      const int cgl = nbase + ni * 16;
      const float bb = bv[cgl];
      const int hh = cgl >> 6, d = cgl & 63;
#pragma unroll
      for (int mi = 0; mi < 4; ++mi) {
        const int m = m0 + wm * 64 + mi * 16 + g4;
        const int t0 = m & 2047, bi = m >> 11;
        const int w64 = t0 & 63;
        const int pos = (t0 & ~63) | (((w64 >> 5) & 1) << 5) | (((w64 >> 2) & 3) << 3) |
                        (((w64 >> 4) & 1) << 2);
        ushort4 o;
        o.x = f2b(acc[mi][ni][0] + bb);
        o.y = f2b(acc[mi][ni][1] + bb);
        o.z = f2b(acc[mi][ni][2] + bb);
        o.w = f2b(acc[mi][ni][3] + bb);
        *(ushort4*)&Vto[(((size_t)bi * HEADS + hh) * DH + d) * TT + pos] = o;
      }
    }
  }
#undef STAGEQ
#undef READQ
#undef MFMAQ
#undef QW3
#undef QW0
}

// ---------------- O-projection GEMM (unchanged from round 11) ----------------
#define SLOT_OA (256 * 32)
#define SLOT_OB (128 * 32)
#define SLOT_OE (SLOT_OA + SLOT_OB)

__global__ __launch_bounds__(512, 2) void gemm_out8(const u16* __restrict__ A,
                                                    const u16* __restrict__ Bw,
                                                    const float* __restrict__ bias,
                                                    float* __restrict__ outp) {
  __shared__ u16 lds[4 * SLOT_OE];  // 96 KB
  const int tid = threadIdx.x, lane = tid & 63, wave = tid >> 6;
  const int fr = lane & 15, g = lane >> 4;
  const int wm = wave >> 1, wn = wave & 1;

  const int bx = blockIdx.x >> 5, by = blockIdx.x & 31;
  const int m0 = by * 256, n0 = bx * 128;

  const int srow = tid >> 2;
  const int schunk = (tid & 3) ^ ((tid >> 3) & 3);
  const u16* gA0 = A + (size_t)(m0 + srow) * DM + schunk * 8;
  const u16* gA1 = gA0 + (size_t)128 * DM;
  const u16* gB0 = Bw + (size_t)(n0 + srow) * DM + schunk * 8;
  const int dA0 = wave * 512;
  const int dA1 = 4096 + wave * 512;
  const int dB0 = SLOT_OA + wave * 512;

#define STAGEO(slot, kt) {                                   \
    u16* ls = &lds[(slot) * SLOT_OE];                        \
    const int ke = (kt) * 32;                                \
    gload_lds16(gA0 + ke, ls + dA0);                         \
    gload_lds16(gA1 + ke, ls + dA1);                         \
    gload_lds16(gB0 + ke, ls + dB0); }

  const int rchunk = (g ^ ((fr >> 1) & 3)) * 8;
  const int offA = (wm * 64 + fr) * 32 + rchunk;
  const int offB = SLOT_OA + (wn * 64 + fr) * 32 + rchunk;

  f32x4 acc[4][4];
#pragma unroll
  for (int mi = 0; mi < 4; ++mi)
#pragma unroll
    for (int ni = 0; ni < 4; ++ni) acc[mi][ni] = (f32x4){0.f, 0.f, 0.f, 0.f};

  bf16x8 afA[4], bfA[4], afB[4], bfB[4];

#define READO(AFv, BFv, kt) {                                \
    const u16* sl = &lds[((kt) & 3) * SLOT_OE];              \
    _Pragma("unroll")                                        \
    for (int mi = 0; mi < 4; ++mi)                           \
      AFv[mi] = *(const bf16x8*)&sl[offA + mi * 512];        \
    _Pragma("unroll")                                        \
    for (int ni = 0; ni < 4; ++ni)                           \
      BFv[ni] = *(const bf16x8*)&sl[offB + ni * 512]; }

#define MFMAO(AFv, BFv) {                                    \
    __builtin_amdgcn_s_setprio(1);                           \
    _Pragma("unroll")                                        \
    for (int mi = 0; mi < 4; ++mi)                           \
      _Pragma("unroll")                                      \
      for (int ni = 0; ni < 4; ++ni)                         \
        acc[mi][ni] = __builtin_amdgcn_mfma_f32_16x16x32_bf16(AFv[mi], BFv[ni], acc[mi][ni], 0, 0, 0); \
    __builtin_amdgcn_s_setprio(0); }

#define OW3 asm volatile("s_waitcnt vmcnt(3)" ::: "memory"); \
            asm volatile("s_barrier" ::: "memory");
#define OW0 asm volatile("s_waitcnt vmcnt(0)" ::: "memory"); \
            asm volatile("s_barrier" ::: "memory");

  STAGEO(0, 0)
  STAGEO(1, 1)
  STAGEO(2, 2)
  asm volatile("s_waitcnt vmcnt(6)" ::: "memory");
  asm volatile("s_barrier" ::: "memory");
  READO(afA, bfA, 0)

  for (int kt = 0; kt < 28; kt += 2) {
    OW3
    READO(afB, bfB, kt + 1)
    MFMAO(afA, bfA)
    STAGEO((kt + 3) & 3, kt + 3)
    OW3
    READO(afA, bfA, kt + 2)
    MFMAO(afB, bfB)
    STAGEO((kt + 4) & 3, kt + 4)
  }
  OW3
  READO(afB, bfB, 29)
  MFMAO(afA, bfA)
  STAGEO(3, 31)
  OW3
  READO(afA, bfA, 30)
  MFMAO(afB, bfB)
  OW0
  READO(afB, bfB, 31)
  MFMAO(afA, bfA)
  MFMAO(afB, bfB)

  const int g4 = g * 4;
#pragma unroll
  for (int mi = 0; mi < 4; ++mi) {
    const int rg = m0 + wm * 64 + mi * 16 + g4;
#pragma unroll
    for (int ni = 0; ni < 4; ++ni) {
      const int cg = n0 + wn * 64 + ni * 16 + fr;
      const float bb = bias[cg];
#pragma unroll
      for (int j = 0; j < 4; ++j)
        outp[(size_t)(rg + j) * DM + cg] = acc[mi][ni][j] + bb;
    }
  }
#undef STAGEO
#undef READO
#undef MFMAO
#undef OW3
#undef OW0
}

// ---------------- flash attention, causal, QBLK=128, gload_lds staging ---------
// Same structure as round 14; ONLY the staging changed: global_load_lds with
// LINEAR LDS dest + inverse-swizzled per-lane GLOBAL source (rule: swizzle
// both sides or neither).  A 1024B gload covers 8 rows; lane l lands at
// LDS[R+(l>>3)][chunk=l&7]; with R%8==0, row&7 == l>>3, so sourcing chunk
// (l&7)^(l>>3) reproduces LDS[row][c] = G[row][c^(row&7)] exactly — the
// swizzled ds_read addresses are byte-identical to round 14.  Per wave per
// tile: 4 async gload instrs replace 4 global loads + vmcnt wait + 4
// ds_write_b128 (LDS-pipe ops 20 -> 16, no reg round-trip).
__global__ __launch_bounds__(256) void attn_fwd(const u16* __restrict__ Q,
                                                const u16* __restrict__ K,
                                                const u16* __restrict__ Vt,
                                                u16* __restrict__ O) {
  const int o_ = blockIdx.x;
  const int xcd = o_ & 7, j = o_ >> 3;     // j in [0,128)
  const int gi = j & 7;                    // group within XCD
  const int qt128 = 15 - (j >> 3);         // descending (LPT)
  const int gidx = xcd * 8 + gi;           // (b,h) group 0..63
  const int b = gidx >> 4, h = gidx & 15;
  const int tid = threadIdx.x, lane = tid & 63, wave = tid >> 6;
  __shared__ u16 Ks[64 * 64];
  __shared__ u16 Vs[64 * 64];

  const size_t bh = ((size_t)b * HEADS + h) * TT;
  const size_t vbse = ((size_t)b * HEADS + h) * DH;
  const int fr = lane & 15, g = lane >> 4;

  // ---- staging: linear LDS dest, inverse-swizzled global source ----
  const int lrow = lane >> 3;                    // 0..7 (row within 8-row region)
  const int lchunk = (lane & 7) ^ lrow;          // source 16B chunk
  const int krow0 = wave * 16 + lrow;            // K tile rows this lane touches
  const int krow1 = krow0 + 8;
  const u16* kSrc0 = &K[(bh + krow0) * DH + lchunk * 8];     // + kv0*DH per tile
  const u16* kSrc1 = &K[(bh + krow1) * DH + lchunk * 8];
  const u16* vSrc0 = &Vt[(vbse + krow0) * TT + lchunk * 8];  // + kv0 per tile
  const u16* vSrc1 = &Vt[(vbse + krow1) * TT + lchunk * 8];
  u16* kDst0 = &Ks[(wave * 16) * 64];            // wave-uniform 1KB regions
  u16* kDst1 = &Ks[(wave * 16 + 8) * 64];
  u16* vDst0 = &Vs[(wave * 16) * 64];
  u16* vDst1 = &Vs[(wave * 16 + 8) * 64];

  const int rk0 = (g ^ (fr & 7)) * 8;
  const int rk1 = ((4 + g) ^ (fr & 7)) * 8;
  const int k8 = g * 8;

  const int q0 = qt128 * 128;
  const int qtL = 2 * qt128, qtH = qtL + 1;
  const int qrowL = q0 + wave * 16 + fr;
  const int qrowH = q0 + 64 + wave * 16 + fr;
  const bf16x8 qfL0 = *(const bf16x8*)&Q[(bh + qrowL) * DH + k8];
  const bf16x8 qfL1 = *(const bf16x8*)&Q[(bh + qrowL) * DH + 32 + k8];
  const bf16x8 qfH0 = *(const bf16x8*)&Q[(bh + qrowH) * DH + k8];
  const bf16x8 qfH1 = *(const bf16x8*)&Q[(bh + qrowH) * DH + 32 + k8];

  float lsumL = 0.f, lsumH = 0.f;
  f32x4 oaccL[4], oaccH[4];
#pragma unroll
  for (int c = 0; c < 4; ++c) {
    oaccL[c] = (f32x4){0.f, 0.f, 0.f, 0.f};
    oaccH[c] = (f32x4){0.f, 0.f, 0.f, 0.f};
  }

  for (int kvb = 0; kvb <= qtH; ++kvb) {
    const int kv0 = kvb * 64;
    gload_lds16(kSrc0 + (size_t)kv0 * DH, kDst0);
    gload_lds16(kSrc1 + (size_t)kv0 * DH, kDst1);
    gload_lds16(vSrc0 + kv0, vDst0);
    gload_lds16(vSrc1 + kv0, vDst1);
    __syncthreads();

    // S^T = K Q for both q-groups; K fragments read ONCE
    f32x4 sL[4], sH[4];
    __builtin_amdgcn_s_setprio(1);
#pragma unroll
    for (int c = 0; c < 4; ++c) {
      bf16x8 kb0 = *(const bf16x8*)&Ks[(c * 16 + fr) * 64 + rk0];
      bf16x8 kb1 = *(const bf16x8*)&Ks[(c * 16 + fr) * 64 + rk1];
      f32x4 tL = (f32x4){0.f, 0.f, 0.f, 0.f};
      tL = __builtin_amdgcn_mfma_f32_16x16x32_bf16(kb0, qfL0, tL, 0, 0, 0);
      tL = __builtin_amdgcn_mfma_f32_16x16x32_bf16(kb1, qfL1, tL, 0, 0, 0);
      sL[c] = tL;
      f32x4 tH = (f32x4){0.f, 0.f, 0.f, 0.f};
      tH = __builtin_amdgcn_mfma_f32_16x16x32_bf16(kb0, qfH0, tH, 0, 0, 0);
      tH = __builtin_amdgcn_mfma_f32_16x16x32_bf16(kb1, qfH1, tH, 0, 0, 0);
      sH[c] = tH;
    }
    __builtin_amdgcn_s_setprio(0);

    if (kvb >= qtL) {  // diagonal band: mask both groups in-lane
#pragma unroll
      for (int c = 0; c < 4; ++c) {
        const int colg = kv0 + c * 16 + 4 * g;
#pragma unroll
        for (int r = 0; r < 4; ++r) {
          if (colg + r > qrowL) sL[c][r] = -1e30f;
          if (colg + r > qrowH) sH[c][r] = -1e30f;
        }
      }
    }

    // p = exp2(s), packed in-register; row-sums
    float rsL = 0.f, rsH = 0.f;
    uint32_t pkL[8], pkH[8];
#pragma unroll
    for (int c = 0; c < 4; ++c) {
      float l0 = __builtin_amdgcn_exp2f(sL[c][0]);
      float l1 = __builtin_amdgcn_exp2f(sL[c][1]);
      float l2 = __builtin_amdgcn_exp2f(sL[c][2]);
      float l3 = __builtin_amdgcn_exp2f(sL[c][3]);
      rsL += (l0 + l1) + (l2 + l3);
      pkL[2 * c] = cvtpk(l0, l1);
      pkL[2 * c + 1] = cvtpk(l2, l3);
      float h0 = __builtin_amdgcn_exp2f(sH[c][0]);
      float h1 = __builtin_amdgcn_exp2f(sH[c][1]);
      float h2 = __builtin_amdgcn_exp2f(sH[c][2]);
      float h3 = __builtin_amdgcn_exp2f(sH[c][3]);
      rsH += (h0 + h1) + (h2 + h3);
      pkH[2 * c] = cvtpk(h0, h1);
      pkH[2 * c + 1] = cvtpk(h2, h3);
    }
    rsL += __shfl_xor(rsL, 16);
    rsL += __shfl_xor(rsL, 32);
    lsumL += rsL;
    rsH += __shfl_xor(rsH, 16);
    rsH += __shfl_xor(rsH, 32);
    lsumH += rsH;

    const bf16x8 paL0 = __builtin_bit_cast(bf16x8, (u32x4){pkL[0], pkL[1], pkL[2], pkL[3]});
    const bf16x8 paL1 = __builtin_bit_cast(bf16x8, (u32x4){pkL[4], pkL[5], pkL[6], pkL[7]});
    const bf16x8 paH0 = __builtin_bit_cast(bf16x8, (u32x4){pkH[0], pkH[1], pkH[2], pkH[3]});
    const bf16x8 paH1 = __builtin_bit_cast(bf16x8, (u32x4){pkH[4], pkH[5], pkH[6], pkH[7]});

    // O^T += V^T P^T for both groups; V fragments read ONCE
    __builtin_amdgcn_s_setprio(1);
#pragma unroll
    for (int c = 0; c < 4; ++c) {
      bf16x8 vb0 = *(const bf16x8*)&Vs[(c * 16 + fr) * 64 + rk0];
      bf16x8 vb1 = *(const bf16x8*)&Vs[(c * 16 + fr) * 64 + rk1];
      oaccL[c] = __builtin_amdgcn_mfma_f32_16x16x32_bf16(vb0, paL0, oaccL[c], 0, 0, 0);
      oaccL[c] = __builtin_amdgcn_mfma_f32_16x16x32_bf16(vb1, paL1, oaccL[c], 0, 0, 0);
      oaccH[c] = __builtin_amdgcn_mfma_f32_16x16x32_bf16(vb0, paH0, oaccH[c], 0, 0, 0);
      oaccH[c] = __builtin_amdgcn_mfma_f32_16x16x32_bf16(vb1, paH1, oaccH[c], 0, 0, 0);
    }
    __builtin_amdgcn_s_setprio(0);
    __syncthreads();
  }

  // epilogues: lane owns O[qrow][d = c*16 + 4g + r]
  const float invL = 1.f / lsumL;
#pragma unroll
  for (int c = 0; c < 4; ++c) {
    ushort4 o;
    o.x = f2b(oaccL[c][0] * invL);
    o.y = f2b(oaccL[c][1] * invL);
    o.z = f2b(oaccL[c][2] * invL);
    o.w = f2b(oaccL[c][3] * invL);
    *(ushort4*)&O[((size_t)b * TT + qrowL) * DM + h * DH + c * 16 + 4 * g] = o;
  }
  const float invH = 1.f / lsumH;
#pragma unroll
  for (int c = 0; c < 4; ++c) {
    ushort4 o;
    o.x = f2b(oaccH[c][0] * invH);
    o.y = f2b(oaccH[c][1] * invH);
    o.z = f2b(oaccH[c][2] * invH);
    o.w = f2b(oaccH[c][3] * invH);
    *(ushort4*)&O[((size_t)b * TT + qrowH) * DM + h * DH + c * 16 + 4 * g] = o;
  }
}

extern "C" void kernel_launch(void* const* d_in, const int* in_sizes, int n_in,
                              void* d_out, int out_size, void* d_ws, size_t ws_size,
                              hipStream_t stream) {
  const float* x  = (const float*)d_in[0];
  const float* Wq = (const float*)d_in[1];
  const float* bq = (const float*)d_in[2];
  const float* Wk = (const float*)d_in[3];
  const float* bk = (const float*)d_in[4];
  const float* Wv = (const float*)d_in[5];
  const float* bv = (const float*)d_in[6];
  const float* Wo = (const float*)d_in[7];
  const float* bo = (const float*)d_in[8];

  char* w = (char*)d_ws;
  u16* xb    = (u16*)w; w += (size_t)MTOT * DM * 2;
  u16* Wqkvb = (u16*)w; w += (size_t)3 * DM * DM * 2;
  u16* Wob   = (u16*)w; w += (size_t)DM * DM * 2;
  u16* Qb    = (u16*)w; w += (size_t)MTOT * DM * 2;
  u16* Kb    = (u16*)w; w += (size_t)MTOT * DM * 2;
  u16* Vtb   = (u16*)w; w += (size_t)MTOT * DM * 2;
  u16* AOb   = (u16*)w; w += (size_t)MTOT * DM * 2;

  cast_all<<<(NX + 4 * NW) / 256, 256, 0, stream>>>(x, Wq, Wk, Wv, Wo, xb, Wqkvb, Wob);

  const float qs = 0.125f * 1.44269504f;  // 1/sqrt(64) * log2(e), folded into Q
  gemm_qkv8<<<768, 512, 0, stream>>>(xb, Wqkvb, bq, bk, bv, Qb, Kb, Vtb, qs);

  attn_fwd<<<1024, 256, 0, stream>>>(Qb, Kb, Vtb, AOb);

  gemm_out8<<<256, 512, 0, stream>>>(AOb, Wob, bo, (float*)d_out);
}

// Round 16
// 155.569 us; speedup vs baseline: 1.0368x; 1.0368x over previous
//
#include <hip/hip_runtime.h>
#include <stdint.h>

#define DM 1024
#define HEADS 16
#define DH 64
#define BQ 4
#define TT 2048
#define MTOT (BQ*TT)  // 8192
#define NQT (TT/64)   // 32 q-tiles per (b,h)

typedef __attribute__((ext_vector_type(8))) __bf16 bf16x8;
typedef __attribute__((ext_vector_type(4))) float f32x4;
typedef __attribute__((ext_vector_type(4))) uint32_t u32x4;
typedef unsigned short u16;
typedef __attribute__((ext_vector_type(8))) unsigned short u16x8;

__device__ __forceinline__ u16 f2b(float f) {
  uint32_t u = __builtin_bit_cast(uint32_t, f);
  u = (u + 0x7fffu + ((u >> 16) & 1u)) >> 16;
  return (u16)u;
}

__device__ __forceinline__ uint32_t cvtpk(float lo, float hi) {
  uint32_t r;
  asm("v_cvt_pk_bf16_f32 %0, %1, %2" : "=v"(r) : "v"(lo), "v"(hi));
  return r;
}

__device__ __forceinline__ void gload_lds16(const u16* g, u16* l) {
  __builtin_amdgcn_global_load_lds(
      (const __attribute__((address_space(1))) void*)g,
      (__attribute__((address_space(3))) void*)l, 16, 0, 0);
}

// ---------------- fused cast: x, Wq|Wk|Wv (contiguous), Wo -> bf16 ----------------
#define NX (MTOT * DM / 4)   // float4s in x
#define NW (DM * DM / 4)     // float4s per weight matrix
__global__ __launch_bounds__(256) void cast_all(const float* __restrict__ x,
                                                const float* __restrict__ Wq,
                                                const float* __restrict__ Wk,
                                                const float* __restrict__ Wv,
                                                const float* __restrict__ Wo,
                                                u16* __restrict__ xb,
                                                u16* __restrict__ wqkvb,
                                                u16* __restrict__ wob) {
  int i = blockIdx.x * 256 + threadIdx.x;
  const float* src; u16* dst;
  if (i < NX)               { src = x;  dst = xb; }
  else if (i < NX + NW)     { src = Wq; dst = wqkvb;          i -= NX; }
  else if (i < NX + 2 * NW) { src = Wk; dst = wqkvb + 4 * NW; i -= NX + NW; }
  else if (i < NX + 3 * NW) { src = Wv; dst = wqkvb + 8 * NW; i -= NX + 2 * NW; }
  else                      { src = Wo; dst = wob;            i -= NX + 3 * NW; }
  float4 v = ((const float4*)src)[i];
  ushort4 o;
  o.x = f2b(v.x); o.y = f2b(v.y); o.z = f2b(v.z); o.w = f2b(v.w);
  ((ushort4*)dst)[i] = o;
}

// ---------------- fused QKV GEMM: BM=256 BN=128 BK=64, 3-slot ring -------------
// 16 K-steps (half the barriers of BK=32).  3 slots x 48KB = 144KB LDS.
// 6 gloads/stage, depth-2 prefetch, vmcnt(6) steady.  Hazard trace: entering a
// body, outstanding = {kt+1, kt+2} (12); QW6 retires kt+1 before READ(kt+1);
// STAGE(kt+2) targets the slot whose reads retired before the PREVIOUS body's
// barrier (issue-after-barrier => land-after-reads).  Tail drains 6 -> 0.
#define NK2 16
#define SLOT_A2 (256 * 64)           // 16384 elems (32KB)
#define SLOT_B2 (128 * 64)           // 8192 elems (16KB)
#define SLOT_E2 (SLOT_A2 + SLOT_B2)  // 24576 elems (48KB)

__global__ __launch_bounds__(512, 2) void gemm_qkv8(const u16* __restrict__ A,
                                                    const u16* __restrict__ W,
                                                    const float* __restrict__ bq,
                                                    const float* __restrict__ bk,
                                                    const float* __restrict__ bv,
                                                    u16* __restrict__ Qo,
                                                    u16* __restrict__ Ko,
                                                    u16* __restrict__ Vto,
                                                    float qs) {
  __shared__ u16 lds[3 * SLOT_E2];  // 144 KB
  const int tid = threadIdx.x, lane = tid & 63, wave = tid >> 6;
  const int fr = lane & 15, g = lane >> 4;
  const int wm = wave >> 1, wn = wave & 1;

  // XCD swizzle: 768 = 8 * 96
  int bid = blockIdx.x;
  bid = (bid & 7) * 96 + (bid >> 3);
  const int by = bid / 24, bx = bid % 24;       // by: m-tile(32), bx: n-tile(24)
  const int m0 = by * 256, n0 = bx * 128;

  // staging: per gload line, wave covers 8 rows; lane l -> row +(l>>3), chunk l&7
  // source chunk inverse-swizzled: (l&7)^(l>>3)  (row&7 == l>>3)
  const int lr8 = lane >> 3;
  const int lsc = ((lane & 7) ^ lr8) * 8;
  const u16* gA0 = A + (size_t)(m0 + wave * 8 + lr8) * DM + lsc;
  const u16* gB0 = W + (size_t)(n0 + wave * 8 + lr8) * DM + lsc;
  const int dA0 = wave * 512;              // elems; lane adds l*8 via HW
  const int dB0 = SLOT_A2 + wave * 512;

#define STAGEQ(ls, kt) {                                     \
    const int ke = (kt) * 64;                                \
    gload_lds16(gA0 + ke,                (ls) + dA0);        \
    gload_lds16(gA0 + ke + (size_t)64  * DM, (ls) + dA0 + 4096);  \
    gload_lds16(gA0 + ke + (size_t)128 * DM, (ls) + dA0 + 8192);  \
    gload_lds16(gA0 + ke + (size_t)192 * DM, (ls) + dA0 + 12288); \
    gload_lds16(gB0 + ke,                (ls) + dB0);        \
    gload_lds16(gB0 + ke + (size_t)64  * DM, (ls) + dB0 + 4096); }

  // read offsets: row = (w*64 + mi*16 + fr), col chunk (hf*4+g)^(fr&7)
  const int rc0 = ((g) ^ (fr & 7)) * 8;
  const int rc1 = ((4 + g) ^ (fr & 7)) * 8;
  const int offA = (wm * 64 + fr) * 64;         // + mi*1024 + rc
  const int offB = SLOT_A2 + (wn * 64 + fr) * 64;

  f32x4 acc[4][4];
#pragma unroll
  for (int mi = 0; mi < 4; ++mi)
#pragma unroll
    for (int ni = 0; ni < 4; ++ni) acc[mi][ni] = (f32x4){0.f, 0.f, 0.f, 0.f};

  bf16x8 afA[8], bfA[8], afB[8], bfB[8];   // [mi*2+hf], [ni*2+hf]

#define READQ(AFv, BFv, ls) {                                \
    _Pragma("unroll")                                        \
    for (int mi = 0; mi < 4; ++mi) {                         \
      AFv[2 * mi]     = *(const bf16x8*)&(ls)[offA + mi * 1024 + rc0]; \
      AFv[2 * mi + 1] = *(const bf16x8*)&(ls)[offA + mi * 1024 + rc1]; \
    }                                                        \
    _Pragma("unroll")                                        \
    for (int ni = 0; ni < 4; ++ni) {                         \
      BFv[2 * ni]     = *(const bf16x8*)&(ls)[offB + ni * 1024 + rc0]; \
      BFv[2 * ni + 1] = *(const bf16x8*)&(ls)[offB + ni * 1024 + rc1]; \
    } }

#define MFMAQ(AFv, BFv) {                                    \
    __builtin_amdgcn_s_setprio(1);                           \
    _Pragma("unroll")                                        \
    for (int mi = 0; mi < 4; ++mi)                           \
      _Pragma("unroll")                                      \
      for (int ni = 0; ni < 4; ++ni) {                       \
        acc[mi][ni] = __builtin_amdgcn_mfma_f32_16x16x32_bf16(AFv[2 * mi], BFv[2 * ni], acc[mi][ni], 0, 0, 0); \
        acc[mi][ni] = __builtin_amdgcn_mfma_f32_16x16x32_bf16(AFv[2 * mi + 1], BFv[2 * ni + 1], acc[mi][ni], 0, 0, 0); \
      }                                                      \
    __builtin_amdgcn_s_setprio(0); }

#define QW6 asm volatile("s_waitcnt vmcnt(6)" ::: "memory"); \
            asm volatile("s_barrier" ::: "memory");
#define QW0 asm volatile("s_waitcnt vmcnt(0)" ::: "memory"); \
            asm volatile("s_barrier" ::: "memory");

  u16* p0 = &lds[0];
  u16* p1 = &lds[SLOT_E2];
  u16* p2 = &lds[2 * SLOT_E2];
  u16 *pCur = p0, *pNxt = p1, *pStg = p2;

  STAGEQ(p0, 0)
  STAGEQ(p1, 1)
  asm volatile("s_waitcnt vmcnt(6)" ::: "memory");
  asm volatile("s_barrier" ::: "memory");
  READQ(afA, bfA, p0)

  for (int kt = 0; kt < NK2 - 2; kt += 2) {
    // body A: compute kt, read kt+1, stage kt+2
    STAGEQ(pStg, kt + 2)
    QW6
    READQ(afB, bfB, pNxt)
    MFMAQ(afA, bfA)
    { u16* t = pCur; pCur = pNxt; pNxt = pStg; pStg = t; }
    // body B: compute kt+1, read kt+2, stage kt+3 (last iter stages NK2-1)
    if (kt + 3 < NK2) { STAGEQ(pStg, kt + 3) }
    QW6
    READQ(afA, bfA, pNxt)
    MFMAQ(afB, bfB)
    { u16* t = pCur; pCur = pNxt; pNxt = pStg; pStg = t; }
  }
  // after loop: MFMA 0..13 done; afA holds frags(14); stage(15) outstanding
  QW0
  READQ(afB, bfB, pNxt)
  MFMAQ(afA, bfA)   // kt = 14
  MFMAQ(afB, bfB)   // kt = 15

  // epilogue: m = m0 + wm*64 + mi*16 + g*4 + j ; n = n0 + wn*64 + ni*16 + fr
  const int g4 = g * 4;
  const int seg = n0 >> 10;
  const int nbase = (n0 & 1023) + wn * 64 + fr;
  if (seg == 0) {
#pragma unroll
    for (int ni = 0; ni < 4; ++ni) {
      const int cgl = nbase + ni * 16;
      const float bb = bq[cgl];
      const int hh = cgl >> 6, d = cgl & 63;
#pragma unroll
      for (int mi = 0; mi < 4; ++mi) {
        const int m = m0 + wm * 64 + mi * 16 + g4;
        const int bi = m >> 11, t = m & 2047;
        u16* dst = &Qo[(((size_t)bi * HEADS + hh) * TT + t) * DH + d];
#pragma unroll
        for (int j = 0; j < 4; ++j)
          dst[(size_t)j * DH] = f2b((acc[mi][ni][j] + bb) * qs);
      }
    }
  } else if (seg == 1) {
#pragma unroll
    for (int ni = 0; ni < 4; ++ni) {
      const int cgl = nbase + ni * 16;
      const float bb = bk[cgl];
      const int hh = cgl >> 6, d = cgl & 63;
#pragma unroll
      for (int mi = 0; mi < 4; ++mi) {
        const int m = m0 + wm * 64 + mi * 16 + g4;
        const int bi = m >> 11, t = m & 2047;
        u16* dst = &Ko[(((size_t)bi * HEADS + hh) * TT + t) * DH + d];
#pragma unroll
        for (int j = 0; j < 4; ++j)
          dst[(size_t)j * DH] = f2b(acc[mi][ni][j] + bb);
      }
    }
  } else {
#pragma unroll
    for (int ni = 0; ni < 4; ++ni) {
      const int cgl = nbase + ni * 16;
      const float bb = bv[cgl];
      const int hh = cgl >> 6, d = cgl & 63;
#pragma unroll
      for (int mi = 0; mi < 4; ++mi) {
        const int m = m0 + wm * 64 + mi * 16 + g4;
        const int t0 = m & 2047, bi = m >> 11;
        const int w64 = t0 & 63;
        const int pos = (t0 & ~63) | (((w64 >> 5) & 1) << 5) | (((w64 >> 2) & 3) << 3) |
                        (((w64 >> 4) & 1) << 2);
        ushort4 o;
        o.x = f2b(acc[mi][ni][0] + bb);
        o.y = f2b(acc[mi][ni][1] + bb);
        o.z = f2b(acc[mi][ni][2] + bb);
        o.w = f2b(acc[mi][ni][3] + bb);
        *(ushort4*)&Vto[(((size_t)bi * HEADS + hh) * DH + d) * TT + pos] = o;
      }
    }
  }
#undef STAGEQ
#undef READQ
#undef MFMAQ
#undef QW6
#undef QW0
}

// ---------------- O-projection GEMM (unchanged from round 11) ----------------
#define SLOT_OA (256 * 32)
#define SLOT_OB (128 * 32)
#define SLOT_OE (SLOT_OA + SLOT_OB)

__global__ __launch_bounds__(512, 2) void gemm_out8(const u16* __restrict__ A,
                                                    const u16* __restrict__ Bw,
                                                    const float* __restrict__ bias,
                                                    float* __restrict__ outp) {
  __shared__ u16 lds[4 * SLOT_OE];  // 96 KB
  const int tid = threadIdx.x, lane = tid & 63, wave = tid >> 6;
  const int fr = lane & 15, g = lane >> 4;
  const int wm = wave >> 1, wn = wave & 1;

  const int bx = blockIdx.x >> 5, by = blockIdx.x & 31;
  const int m0 = by * 256, n0 = bx * 128;

  const int srow = tid >> 2;
  const int schunk = (tid & 3) ^ ((tid >> 3) & 3);
  const u16* gA0 = A + (size_t)(m0 + srow) * DM + schunk * 8;
  const u16* gA1 = gA0 + (size_t)128 * DM;
  const u16* gB0 = Bw + (size_t)(n0 + srow) * DM + schunk * 8;
  const int dA0 = wave * 512;
  const int dA1 = 4096 + wave * 512;
  const int dB0 = SLOT_OA + wave * 512;

#define STAGEO(slot, kt) {                                   \
    u16* ls = &lds[(slot) * SLOT_OE];                        \
    const int ke = (kt) * 32;                                \
    gload_lds16(gA0 + ke, ls + dA0);                         \
    gload_lds16(gA1 + ke, ls + dA1);                         \
    gload_lds16(gB0 + ke, ls + dB0); }

  const int rchunk = (g ^ ((fr >> 1) & 3)) * 8;
  const int offA = (wm * 64 + fr) * 32 + rchunk;
  const int offB = SLOT_OA + (wn * 64 + fr) * 32 + rchunk;

  f32x4 acc[4][4];
#pragma unroll
  for (int mi = 0; mi < 4; ++mi)
#pragma unroll
    for (int ni = 0; ni < 4; ++ni) acc[mi][ni] = (f32x4){0.f, 0.f, 0.f, 0.f};

  bf16x8 afA[4], bfA[4], afB[4], bfB[4];

#define READO(AFv, BFv, kt) {                                \
    const u16* sl = &lds[((kt) & 3) * SLOT_OE];              \
    _Pragma("unroll")                                        \
    for (int mi = 0; mi < 4; ++mi)                           \
      AFv[mi] = *(const bf16x8*)&sl[offA + mi * 512];        \
    _Pragma("unroll")                                        \
    for (int ni = 0; ni < 4; ++ni)                           \
      BFv[ni] = *(const bf16x8*)&sl[offB + ni * 512]; }

#define MFMAO(AFv, BFv) {                                    \
    __builtin_amdgcn_s_setprio(1);                           \
    _Pragma("unroll")                                        \
    for (int mi = 0; mi < 4; ++mi)                           \
      _Pragma("unroll")                                      \
      for (int ni = 0; ni < 4; ++ni)                         \
        acc[mi][ni] = __builtin_amdgcn_mfma_f32_16x16x32_bf16(AFv[mi], BFv[ni], acc[mi][ni], 0, 0, 0); \
    __builtin_amdgcn_s_setprio(0); }

#define OW3 asm volatile("s_waitcnt vmcnt(3)" ::: "memory"); \
            asm volatile("s_barrier" ::: "memory");
#define OW0 asm volatile("s_waitcnt vmcnt(0)" ::: "memory"); \
            asm volatile("s_barrier" ::: "memory");

  STAGEO(0, 0)
  STAGEO(1, 1)
  STAGEO(2, 2)
  asm volatile("s_waitcnt vmcnt(6)" ::: "memory");
  asm volatile("s_barrier" ::: "memory");
  READO(afA, bfA, 0)

  for (int kt = 0; kt < 28; kt += 2) {
    OW3
    READO(afB, bfB, kt + 1)
    MFMAO(afA, bfA)
    STAGEO((kt + 3) & 3, kt + 3)
    OW3
    READO(afA, bfA, kt + 2)
    MFMAO(afB, bfB)
    STAGEO((kt + 4) & 3, kt + 4)
  }
  OW3
  READO(afB, bfB, 29)
  MFMAO(afA, bfA)
  STAGEO(3, 31)
  OW3
  READO(afA, bfA, 30)
  MFMAO(afB, bfB)
  OW0
  READO(afB, bfB, 31)
  MFMAO(afA, bfA)
  MFMAO(afB, bfB)

  const int g4 = g * 4;
#pragma unroll
  for (int mi = 0; mi < 4; ++mi) {
    const int rg = m0 + wm * 64 + mi * 16 + g4;
#pragma unroll
    for (int ni = 0; ni < 4; ++ni) {
      const int cg = n0 + wn * 64 + ni * 16 + fr;
      const float bb = bias[cg];
#pragma unroll
      for (int j = 0; j < 4; ++j)
        outp[(size_t)(rg + j) * DM + cg] = acc[mi][ni][j] + bb;
    }
  }
#undef STAGEO
#undef READO
#undef MFMAO
#undef OW3
#undef OW0
}

// ---------------- flash attention, causal, QBLK=128 (round-14 version) --------
// Reverted to reg-staging: global loads to registers can be hoisted by the
// compiler above the trailing barrier, hiding L2/HBM latency under compute
// (round-15's gload_lds staging lost that overlap and regressed +6us).
__global__ __launch_bounds__(256) void attn_fwd(const u16* __restrict__ Q,
                                                const u16* __restrict__ K,
                                                const u16* __restrict__ Vt,
                                                u16* __restrict__ O) {
  const int o_ = blockIdx.x;
  const int xcd = o_ & 7, j = o_ >> 3;     // j in [0,128)
  const int gi = j & 7;                    // group within XCD
  const int qt128 = 15 - (j >> 3);         // descending (LPT)
  const int gidx = xcd * 8 + gi;           // (b,h) group 0..63
  const int b = gidx >> 4, h = gidx & 15;
  const int tid = threadIdx.x, lane = tid & 63, wave = tid >> 6;
  __shared__ u16 Ks[64 * 64];
  __shared__ u16 Vs[64 * 64];

  const size_t bh = ((size_t)b * HEADS + h) * TT;
  const size_t vbse = ((size_t)b * HEADS + h) * DH;
  const int fr = lane & 15, g = lane >> 4;
  const int sr = tid >> 2;
  const int sc0 = tid & 3;

  const int sw1 = (sc0 ^ (sr & 7)) * 8;
  const int sw2 = ((sc0 + 4) ^ (sr & 7)) * 8;
  const int sgc = sc0 * 8;
  const int rk0 = (g ^ (fr & 7)) * 8;
  const int rk1 = ((4 + g) ^ (fr & 7)) * 8;
  const int k8 = g * 8;

  const int q0 = qt128 * 128;
  const int qtL = 2 * qt128, qtH = qtL + 1;
  const int qrowL = q0 + wave * 16 + fr;
  const int qrowH = q0 + 64 + wave * 16 + fr;
  const bf16x8 qfL0 = *(const bf16x8*)&Q[(bh + qrowL) * DH + k8];
  const bf16x8 qfL1 = *(const bf16x8*)&Q[(bh + qrowL) * DH + 32 + k8];
  const bf16x8 qfH0 = *(const bf16x8*)&Q[(bh + qrowH) * DH + k8];
  const bf16x8 qfH1 = *(const bf16x8*)&Q[(bh + qrowH) * DH + 32 + k8];

  float lsumL = 0.f, lsumH = 0.f;
  f32x4 oaccL[4], oaccH[4];
#pragma unroll
  for (int c = 0; c < 4; ++c) {
    oaccL[c] = (f32x4){0.f, 0.f, 0.f, 0.f};
    oaccH[c] = (f32x4){0.f, 0.f, 0.f, 0.f};
  }

  for (int kvb = 0; kvb <= qtH; ++kvb) {
    const int kv0 = kvb * 64;
    {
      const u16* kg = &K[(bh + kv0 + sr) * DH + sgc];
      u16x8 ka = *(const u16x8*)kg;
      u16x8 kc = *(const u16x8*)(kg + 32);
      const u16* vg = &Vt[(vbse + sr) * TT + kv0 + sgc];
      u16x8 va = *(const u16x8*)vg;
      u16x8 vc = *(const u16x8*)(vg + 32);
      *(u16x8*)&Ks[sr * 64 + sw1] = ka;
      *(u16x8*)&Ks[sr * 64 + sw2] = kc;
      *(u16x8*)&Vs[sr * 64 + sw1] = va;
      *(u16x8*)&Vs[sr * 64 + sw2] = vc;
    }
    __syncthreads();

    // S^T = K Q for both q-groups; K fragments read ONCE
    f32x4 sL[4], sH[4];
    __builtin_amdgcn_s_setprio(1);
#pragma unroll
    for (int c = 0; c < 4; ++c) {
      bf16x8 kb0 = *(const bf16x8*)&Ks[(c * 16 + fr) * 64 + rk0];
      bf16x8 kb1 = *(const bf16x8*)&Ks[(c * 16 + fr) * 64 + rk1];
      f32x4 tL = (f32x4){0.f, 0.f, 0.f, 0.f};
      tL = __builtin_amdgcn_mfma_f32_16x16x32_bf16(kb0, qfL0, tL, 0, 0, 0);
      tL = __builtin_amdgcn_mfma_f32_16x16x32_bf16(kb1, qfL1, tL, 0, 0, 0);
      sL[c] = tL;
      f32x4 tH = (f32x4){0.f, 0.f, 0.f, 0.f};
      tH = __builtin_amdgcn_mfma_f32_16x16x32_bf16(kb0, qfH0, tH, 0, 0, 0);
      tH = __builtin_amdgcn_mfma_f32_16x16x32_bf16(kb1, qfH1, tH, 0, 0, 0);
      sH[c] = tH;
    }
    __builtin_amdgcn_s_setprio(0);

    if (kvb >= qtL) {  // diagonal band: mask both groups in-lane
#pragma unroll
      for (int c = 0; c < 4; ++c) {
        const int colg = kv0 + c * 16 + 4 * g;
#pragma unroll
        for (int r = 0; r < 4; ++r) {
          if (colg + r > qrowL) sL[c][r] = -1e30f;
          if (colg + r > qrowH) sH[c][r] = -1e30f;
        }
      }
    }

    // p = exp2(s), packed in-register; row-sums
    float rsL = 0.f, rsH = 0.f;
    uint32_t pkL[8], pkH[8];
#pragma unroll
    for (int c = 0; c < 4; ++c) {
      float l0 = __builtin_amdgcn_exp2f(sL[c][0]);
      float l1 = __builtin_amdgcn_exp2f(sL[c][1]);
      float l2 = __builtin_amdgcn_exp2f(sL[c][2]);
      float l3 = __builtin_amdgcn_exp2f(sL[c][3]);
      rsL += (l0 + l1) + (l2 + l3);
      pkL[2 * c] = cvtpk(l0, l1);
      pkL[2 * c + 1] = cvtpk(l2, l3);
      float h0 = __builtin_amdgcn_exp2f(sH[c][0]);
      float h1 = __builtin_amdgcn_exp2f(sH[c][1]);
      float h2 = __builtin_amdgcn_exp2f(sH[c][2]);
      float h3 = __builtin_amdgcn_exp2f(sH[c][3]);
      rsH += (h0 + h1) + (h2 + h3);
      pkH[2 * c] = cvtpk(h0, h1);
      pkH[2 * c + 1] = cvtpk(h2, h3);
    }
    rsL += __shfl_xor(rsL, 16);
    rsL += __shfl_xor(rsL, 32);
    lsumL += rsL;
    rsH += __shfl_xor(rsH, 16);
    rsH += __shfl_xor(rsH, 32);
    lsumH += rsH;

    const bf16x8 paL0 = __builtin_bit_cast(bf16x8, (u32x4){pkL[0], pkL[1], pkL[2], pkL[3]});
    const bf16x8 paL1 = __builtin_bit_cast(bf16x8, (u32x4){pkL[4], pkL[5], pkL[6], pkL[7]});
    const bf16x8 paH0 = __builtin_bit_cast(bf16x8, (u32x4){pkH[0], pkH[1], pkH[2], pkH[3]});
    const bf16x8 paH1 = __builtin_bit_cast(bf16x8, (u32x4){pkH[4], pkH[5], pkH[6], pkH[7]});

    // O^T += V^T P^T for both groups; V fragments read ONCE
    __builtin_amdgcn_s_setprio(1);
#pragma unroll
    for (int c = 0; c < 4; ++c) {
      bf16x8 vb0 = *(const bf16x8*)&Vs[(c * 16 + fr) * 64 + rk0];
      bf16x8 vb1 = *(const bf16x8*)&Vs[(c * 16 + fr) * 64 + rk1];
      oaccL[c] = __builtin_amdgcn_mfma_f32_16x16x32_bf16(vb0, paL0, oaccL[c], 0, 0, 0);
      oaccL[c] = __builtin_amdgcn_mfma_f32_16x16x32_bf16(vb1, paL1, oaccL[c], 0, 0, 0);
      oaccH[c] = __builtin_amdgcn_mfma_f32_16x16x32_bf16(vb0, paH0, oaccH[c], 0, 0, 0);
      oaccH[c] = __builtin_amdgcn_mfma_f32_16x16x32_bf16(vb1, paH1, oaccH[c], 0, 0, 0);
    }
    __builtin_amdgcn_s_setprio(0);
    __syncthreads();
  }

  // epilogues: lane owns O[qrow][d = c*16 + 4g + r]
  const float invL = 1.f / lsumL;
#pragma unroll
  for (int c = 0; c < 4; ++c) {
    ushort4 o;
    o.x = f2b(oaccL[c][0] * invL);
    o.y = f2b(oaccL[c][1] * invL);
    o.z = f2b(oaccL[c][2] * invL);
    o.w = f2b(oaccL[c][3] * invL);
    *(ushort4*)&O[((size_t)b * TT + qrowL) * DM + h * DH + c * 16 + 4 * g] = o;
  }
  const float invH = 1.f / lsumH;
#pragma unroll
  for (int c = 0; c < 4; ++c) {
    ushort4 o;
    o.x = f2b(oaccH[c][0] * invH);
    o.y = f2b(oaccH[c][1] * invH);
    o.z = f2b(oaccH[c][2] * invH);
    o.w = f2b(oaccH[c][3] * invH);
    *(ushort4*)&O[((size_t)b * TT + qrowH) * DM + h * DH + c * 16 + 4 * g] = o;
  }
}

extern "C" void kernel_launch(void* const* d_in, const int* in_sizes, int n_in,
                              void* d_out, int out_size, void* d_ws, size_t ws_size,
                              hipStream_t stream) {
  const float* x  = (const float*)d_in[0];
  const float* Wq = (const float*)d_in[1];
  const float* bq = (const float*)d_in[2];
  const float* Wk = (const float*)d_in[3];
  const float* bk = (const float*)d_in[4];
  const float* Wv = (const float*)d_in[5];
  const float* bv = (const float*)d_in[6];
  const float* Wo = (const float*)d_in[7];
  const float* bo = (const float*)d_in[8];

  char* w = (char*)d_ws;
  u16* xb    = (u16*)w; w += (size_t)MTOT * DM * 2;
  u16* Wqkvb = (u16*)w; w += (size_t)3 * DM * DM * 2;
  u16* Wob   = (u16*)w; w += (size_t)DM * DM * 2;
  u16* Qb    = (u16*)w; w += (size_t)MTOT * DM * 2;
  u16* Kb    = (u16*)w; w += (size_t)MTOT * DM * 2;
  u16* Vtb   = (u16*)w; w += (size_t)MTOT * DM * 2;
  u16* AOb   = (u16*)w; w += (size_t)MTOT * DM * 2;

  cast_all<<<(NX + 4 * NW) / 256, 256, 0, stream>>>(x, Wq, Wk, Wv, Wo, xb, Wqkvb, Wob);

  const float qs = 0.125f * 1.44269504f;  // 1/sqrt(64) * log2(e), folded into Q
  gemm_qkv8<<<768, 512, 0, stream>>>(xb, Wqkvb, bq, bk, bv, Qb, Kb, Vtb, qs);

  attn_fwd<<<1024, 256, 0, stream>>>(Qb, Kb, Vtb, AOb);

  gemm_out8<<<256, 512, 0, stream>>>(AOb, Wob, bo, (float*)d_out);
}